// Round 1
// baseline (245.868 us; speedup 1.0000x reference)
//
#include <hip/hip_runtime.h>
#include <hip/hip_bf16.h>

// Cost volume: out[b, k, h, w] = (1/81) * sum_c x1[b,c,h,w] * x2[b,c,h-i,w-j]
// k = (9i + j) mod 81, i,j in [-4,4], zero outside bounds.
// B=4 C=128 H=128 W=256, fp32 in/out.
//
// Design (round 1):
//  - block = 9 waves (576 thr); wave ii handles displacement row i = ii-4.
//  - tile = 8h x 32w pixels per block; lane = (hl, g) covers 4 consecutive w.
//  - 36 fp32 accumulators per lane (9 j x 4 pixels), C-reduction in regs.
//  - LDS staging in 8-channel chunks: x1 8x32, x2 16x40 (halo), 28 KiB.
//  - per channel per lane: 4x ds_read_b128 -> 36 v_fmac_f32 (FMA-dominant).

#define BB 4
#define CC_TOT 128
#define HH 128
#define WW 256
#define RR 4
#define DD 81
#define TH 8
#define TW 32
#define CCHUNK 8
#define X2H (TH + 2 * RR)  // 16
#define X2W (TW + 2 * RR)  // 40
#define NTHREADS 576       // 9 waves

__global__ __launch_bounds__(NTHREADS) void cost_volume_kernel(
    const float* __restrict__ x1, const float* __restrict__ x2,
    float* __restrict__ out) {
  __shared__ float s_x1[CCHUNK][TH][TW];    // 8 KiB
  __shared__ float s_x2[CCHUNK][X2H][X2W];  // 20 KiB

  const int b = blockIdx.z;
  const int h0 = blockIdx.y * TH;
  const int w0 = blockIdx.x * TW;

  const int t = threadIdx.x;
  const int wv = t >> 6;    // 0..8  -> ii (displacement row)
  const int lane = t & 63;
  const int hl = lane >> 3; // 0..7  local h row
  const int g = lane & 7;   // 0..7  group of 4 w pixels

  float acc[9][4];
#pragma unroll
  for (int jj = 0; jj < 9; ++jj)
#pragma unroll
    for (int p = 0; p < 4; ++p) acc[jj][p] = 0.f;

  const float* x1b = x1 + (size_t)b * CC_TOT * HH * WW;
  const float* x2b = x2 + (size_t)b * CC_TOT * HH * WW;

  for (int c0 = 0; c0 < CC_TOT; c0 += CCHUNK) {
    // ---- stage x1: 8 ch x 8 rows x 8 float4 = 512 float4 ----
    if (t < 512) {
      const int ci = t >> 6;
      const int hh = (t >> 3) & 7;
      const int gg = t & 7;
      const float4 v = *(const float4*)(
          x1b + ((size_t)(c0 + ci) * HH + (h0 + hh)) * WW + w0 + gg * 4);
      *(float4*)&s_x1[ci][hh][gg * 4] = v;
    }
    // ---- stage x2: 8 ch x 16 rows x 10 float4 = 1280 float4 ----
#pragma unroll
    for (int it = 0; it < 3; ++it) {
      const int idx = t + it * NTHREADS;
      if (idx < CCHUNK * X2H * 10) {
        const int ci = idx / (X2H * 10);
        const int rem = idx - ci * (X2H * 10);
        const int r = rem / 10;
        const int c4 = rem - r * 10;
        const int gh = h0 - RR + r;
        const int gw = w0 - RR + c4 * 4;
        float4 v = make_float4(0.f, 0.f, 0.f, 0.f);
        if ((unsigned)gh < (unsigned)HH && (unsigned)gw < (unsigned)WW) {
          v = *(const float4*)(x2b + ((size_t)(c0 + ci) * HH + gh) * WW + gw);
        }
        *(float4*)&s_x2[ci][r][c4 * 4] = v;
      }
    }
    __syncthreads();

    // ---- compute: per channel, 4 b128 LDS reads feed 36 FMAs ----
    const int r = hl + 8 - wv;  // x2 local row for this wave's displacement
#pragma unroll
    for (int ci = 0; ci < CCHUNK; ++ci) {
      float xv[4];
      *(float4*)xv = *(const float4*)&s_x1[ci][hl][g * 4];
      float v[12];
      *(float4*)&v[0] = *(const float4*)&s_x2[ci][r][g * 4];
      *(float4*)&v[4] = *(const float4*)&s_x2[ci][r][g * 4 + 4];
      *(float4*)&v[8] = *(const float4*)&s_x2[ci][r][g * 4 + 8];
#pragma unroll
      for (int jj = 0; jj < 9; ++jj)
#pragma unroll
        for (int p = 0; p < 4; ++p)
          acc[jj][p] = fmaf(xv[p], v[p + 8 - jj], acc[jj][p]);
    }
    __syncthreads();
  }

  // ---- epilogue: k = (9*ii + jj + 41) % 81, scaled by 1/81 ----
  const float scale = 1.0f / 81.0f;
#pragma unroll
  for (int jj = 0; jj < 9; ++jj) {
    const int k = (9 * wv + jj + 41) % 81;
    float4 o;
    o.x = acc[jj][0] * scale;
    o.y = acc[jj][1] * scale;
    o.z = acc[jj][2] * scale;
    o.w = acc[jj][3] * scale;
    *(float4*)(out + (((size_t)b * DD + k) * HH + (h0 + hl)) * WW + w0 +
               g * 4) = o;
  }
}

extern "C" void kernel_launch(void* const* d_in, const int* in_sizes, int n_in,
                              void* d_out, int out_size, void* d_ws,
                              size_t ws_size, hipStream_t stream) {
  const float* x1 = (const float*)d_in[0];
  const float* x2 = (const float*)d_in[1];
  float* out = (float*)d_out;

  dim3 grid(WW / TW, HH / TH, BB);  // 8 x 16 x 4 = 512 blocks
  dim3 block(NTHREADS);
  hipLaunchKernelGGL(cost_volume_kernel, grid, block, 0, stream, x1, x2, out);
}